// Round 5
// baseline (54.213 us; speedup 1.0000x reference)
//
#include <hip/hip_runtime.h>

// BasisVQ: quantized[b,k,:] = basis[argmax_c latent[b,k,c], :]
//          indices[b,k]     = argmax_c latent[b,k,c]
// B=16, K=2048, C=1024, D=900. Output = [quantized (B*K*D f32), indices (B*K as f32)].
//
// R5: persistent grid-stride waves (2048 blocks = 8192 waves, exactly resident
// at 8 waves/SIMD) with one-deep latent prefetch. Rationale: all short-wave
// variants (R1-R4, incl. the pure-read split K1) plateau at ~5 TB/s; the 6.3
// TB/s copy ubench uses persistent waves with continuous issue. Loop-carried
// double buffer keeps staging at 2x16 VGPR (R4's flat unroll blew occupancy).

#define C_DIM 1024
#define D_DIM 900

typedef float vfloat4 __attribute__((ext_vector_type(4)));

__device__ __forceinline__ int wave_argmax(vfloat4 v0, vfloat4 v1, vfloat4 v2,
                                           vfloat4 v3, int lane) {
    // per-lane argmax over 16 elems, first-index-wins (ascending, strict >)
    float m = v0[0];
    int   mi = lane * 4;
    #pragma unroll
    for (int e = 1; e < 4; ++e)
        if (v0[e] > m) { m = v0[e]; mi = lane * 4 + e; }
    #pragma unroll
    for (int e = 0; e < 4; ++e)
        if (v1[e] > m) { m = v1[e]; mi = (64 + lane) * 4 + e; }
    #pragma unroll
    for (int e = 0; e < 4; ++e)
        if (v2[e] > m) { m = v2[e]; mi = (128 + lane) * 4 + e; }
    #pragma unroll
    for (int e = 0; e < 4; ++e)
        if (v3[e] > m) { m = v3[e]; mi = (192 + lane) * 4 + e; }

    // wave(64) butterfly argmax, tie -> lowest index (matches jnp.argmax)
    #pragma unroll
    for (int off = 32; off > 0; off >>= 1) {
        float om = __shfl_xor(m, off, 64);
        int   oi = __shfl_xor(mi, off, 64);
        if (om > m || (om == m && oi < mi)) { m = om; mi = oi; }
    }
    return mi;
}

__global__ __launch_bounds__(256) void basisvq_kernel(
    const float* __restrict__ latent,   // [ROWS, 1024]
    const float* __restrict__ basis,    // [1024, 900]
    float* __restrict__ out_q,          // [ROWS, 900]
    float* __restrict__ out_idx,        // [ROWS]
    int rows)
{
    const int lane = threadIdx.x & 63;
    const int wv   = blockIdx.x * 4 + (threadIdx.x >> 6);   // global wave id
    const int NW   = gridDim.x * 4;                          // total waves (8192)

    int row = wv;
    vfloat4 c0, c1, c2, c3;
    if (row < rows) {
        const vfloat4* lr = reinterpret_cast<const vfloat4*>(latent + (size_t)row * C_DIM);
        c0 = __builtin_nontemporal_load(&lr[lane]);
        c1 = __builtin_nontemporal_load(&lr[lane + 64]);
        c2 = __builtin_nontemporal_load(&lr[lane + 128]);
        c3 = __builtin_nontemporal_load(&lr[lane + 192]);
    }

    while (row < rows) {
        const int nrow = row + NW;

        // ---- prefetch next row while current row's pipeline runs ----
        vfloat4 n0, n1, n2, n3;
        if (nrow < rows) {
            const vfloat4* ln = reinterpret_cast<const vfloat4*>(latent + (size_t)nrow * C_DIM);
            n0 = __builtin_nontemporal_load(&ln[lane]);
            n1 = __builtin_nontemporal_load(&ln[lane + 64]);
            n2 = __builtin_nontemporal_load(&ln[lane + 128]);
            n3 = __builtin_nontemporal_load(&ln[lane + 192]);
        }

        // ---- current row: reduce (waits only on c*), idx, gather, store ----
        const int idx = wave_argmax(c0, c1, c2, c3, lane);
        if (lane == 0) out_idx[row] = (float)idx;

        const vfloat4* b4 = reinterpret_cast<const vfloat4*>(basis + (size_t)idx * D_DIM);
        vfloat4*       o4 = reinterpret_cast<vfloat4*>(out_q + (size_t)row * D_DIM);
        #pragma unroll
        for (int j = 0; j < 4; ++j) {
            int t = 64 * j + lane;
            if (t < 225) {
                vfloat4 bv = b4[t];                       // cacheable: basis stays in L2
                __builtin_nontemporal_store(bv, &o4[t]);  // stream out
            }
        }

        row = nrow;
        c0 = n0; c1 = n1; c2 = n2; c3 = n3;
    }
}

extern "C" void kernel_launch(void* const* d_in, const int* in_sizes, int n_in,
                              void* d_out, int out_size, void* d_ws, size_t ws_size,
                              hipStream_t stream) {
    const float* latent = (const float*)d_in[0];   // 16*2048*1024
    const float* basis  = (const float*)d_in[1];   // 1024*900
    (void)n_in; (void)d_ws; (void)ws_size; (void)out_size;

    const int rows = in_sizes[0] / C_DIM;          // 32768
    float* out_q   = (float*)d_out;                // rows*900
    float* out_idx = (float*)d_out + (size_t)rows * D_DIM;

    // 2048 blocks x 4 waves = 8192 persistent waves (8/SIMD at <=64 VGPR),
    // each grid-striding over rows/8192 = 4 rows with one-deep prefetch.
    const int blocks = 2048;
    basisvq_kernel<<<blocks, 256, 0, stream>>>(latent, basis, out_q, out_idx, rows);
}

// Round 6
// 53.590 us; speedup vs baseline: 1.0116x; 1.0116x over previous
//
#include <hip/hip_runtime.h>

// BasisVQ: quantized[b,k,:] = basis[argmax_c latent[b,k,c], :]
//          indices[b,k]     = argmax_c latent[b,k,c]
// B=16, K=2048, C=1024, D=900. Output = [quantized (B*K*D f32), indices (B*K as f32)].
//
// R6: exact R2 structure (one wave per row, 4 waves/block, butterfly argmax,
// no LDS/barriers) with ALL nontemporal flags removed — isolating the nt knob.
// Rationale: R3 showed even a pure-read pass runs at ~5 TB/s (mixing isn't the
// limit); R4/R5 showed deeper staging trips the 64-VGPR occupancy cliff. The
// 6.3-7.2 TB/s ceilings (copy ubench, fillBuffer) are achieved with REGULAR
// cached accesses; nt was never isolated vs R2's structural change.

#define C_DIM 1024
#define D_DIM 900

typedef float vfloat4 __attribute__((ext_vector_type(4)));

__global__ __launch_bounds__(256) void basisvq_kernel(
    const float* __restrict__ latent,   // [ROWS, 1024]
    const float* __restrict__ basis,    // [1024, 900]
    float* __restrict__ out_q,          // [ROWS, 900]
    float* __restrict__ out_idx,        // [ROWS]
    int rows)
{
    const int lane = threadIdx.x & 63;
    const int wid  = threadIdx.x >> 6;
    const int row  = blockIdx.x * 4 + wid;
    if (row >= rows) return;

    // ---- load 16 latent floats/lane as 4 independent float4 (regular, cached) ----
    const vfloat4* lrow = reinterpret_cast<const vfloat4*>(latent + (size_t)row * C_DIM);
    vfloat4 v0 = lrow[lane];
    vfloat4 v1 = lrow[lane + 64];
    vfloat4 v2 = lrow[lane + 128];
    vfloat4 v3 = lrow[lane + 192];

    // ---- per-lane argmax, first-index-wins (ascending scan, strict >) ----
    float m = v0[0];
    int   mi = lane * 4;
    #pragma unroll
    for (int e = 1; e < 4; ++e)
        if (v0[e] > m) { m = v0[e]; mi = lane * 4 + e; }
    #pragma unroll
    for (int e = 0; e < 4; ++e)
        if (v1[e] > m) { m = v1[e]; mi = (64 + lane) * 4 + e; }
    #pragma unroll
    for (int e = 0; e < 4; ++e)
        if (v2[e] > m) { m = v2[e]; mi = (128 + lane) * 4 + e; }
    #pragma unroll
    for (int e = 0; e < 4; ++e)
        if (v3[e] > m) { m = v3[e]; mi = (192 + lane) * 4 + e; }

    // ---- wave(64) butterfly argmax, tie -> lowest index (matches jnp.argmax) ----
    #pragma unroll
    for (int off = 32; off > 0; off >>= 1) {
        float om = __shfl_xor(m, off, 64);
        int   oi = __shfl_xor(mi, off, 64);
        if (om > m || (om == m && oi < mi)) { m = om; mi = oi; }
    }
    const int idx = mi;   // all lanes agree after butterfly

    if (lane == 0) out_idx[row] = (float)idx;

    // ---- gather basis[idx] -> out_q[row] (regular cached loads + stores) ----
    const vfloat4* b4 = reinterpret_cast<const vfloat4*>(basis + (size_t)idx * D_DIM);
    vfloat4*       o4 = reinterpret_cast<vfloat4*>(out_q + (size_t)row * D_DIM);
    #pragma unroll
    for (int j = 0; j < 4; ++j) {
        int t = 64 * j + lane;
        if (t < 225) {
            o4[t] = b4[t];
        }
    }
}

extern "C" void kernel_launch(void* const* d_in, const int* in_sizes, int n_in,
                              void* d_out, int out_size, void* d_ws, size_t ws_size,
                              hipStream_t stream) {
    const float* latent = (const float*)d_in[0];   // 16*2048*1024
    const float* basis  = (const float*)d_in[1];   // 1024*900
    (void)n_in; (void)d_ws; (void)ws_size; (void)out_size;

    const int rows = in_sizes[0] / C_DIM;          // 32768
    float* out_q   = (float*)d_out;                // rows*900
    float* out_idx = (float*)d_out + (size_t)rows * D_DIM;

    const int blocks = (rows + 3) / 4;             // 4 rows (waves) per block
    basisvq_kernel<<<blocks, 256, 0, stream>>>(latent, basis, out_q, out_idx, rows);
}